// Round 1
// baseline (781.365 us; speedup 1.0000x reference)
//
#include <hip/hip_runtime.h>
#include <cstdint>
#include <cstddef>

#define NB 64
#define NN 2048
#define ND 128
#define NK 1024
#define NTOT (NB * NN)        // 131072
#define NE (NB * NN * 32)     // 4194304

// ---------------- degree counting (4 edges / thread) ----------------
__global__ void k_degrees(const int4* __restrict__ src4, const int4* __restrict__ dst4,
                          float* __restrict__ outdeg, float* __restrict__ indeg) {
    int i = blockIdx.x * blockDim.x + threadIdx.x;   // NE/4 threads
    int4 s = src4[i];
    int4 d = dst4[i];
    atomicAdd(&outdeg[s.x], 1.0f); atomicAdd(&outdeg[s.y], 1.0f);
    atomicAdd(&outdeg[s.z], 1.0f); atomicAdd(&outdeg[s.w], 1.0f);
    atomicAdd(&indeg[d.x], 1.0f);  atomicAdd(&indeg[d.y], 1.0f);
    atomicAdd(&indeg[d.z], 1.0f);  atomicAdd(&indeg[d.w], 1.0f);
}

// ---------------- s = feature @ W, one wave (64 lanes) per node ----------------
__global__ void k_project(const float* __restrict__ feat, const float* __restrict__ W,
                          float* __restrict__ s) {
    int gtid = blockIdx.x * blockDim.x + threadIdx.x;
    int node = gtid >> 6;
    int lane = threadIdx.x & 63;
    const float2* f2 = (const float2*)(feat + (size_t)node * ND);
    float2 v  = f2[lane];
    float2 w2 = ((const float2*)W)[lane];
    float val = v.x * w2.x + v.y * w2.y;
    #pragma unroll
    for (int off = 32; off > 0; off >>= 1) val += __shfl_down(val, off);
    if (lane == 0) s[node] = val;
}

// ---------------- m = s * rsqrt(max(outdeg,1)) ----------------
__global__ void k_msg(const float* __restrict__ s, const float* __restrict__ outdeg,
                      float* __restrict__ m) {
    int i = blockIdx.x * blockDim.x + threadIdx.x;
    m[i] = s[i] * (1.0f / sqrtf(fmaxf(outdeg[i], 1.0f)));
}

// ---------------- acc[dst] += m[src] (4 edges / thread) ----------------
__global__ void k_scatter(const int4* __restrict__ src4, const int4* __restrict__ dst4,
                          const float* __restrict__ m, float* __restrict__ acc) {
    int i = blockIdx.x * blockDim.x + threadIdx.x;   // NE/4 threads
    int4 s = src4[i];
    int4 d = dst4[i];
    atomicAdd(&acc[d.x], m[s.x]);
    atomicAdd(&acc[d.y], m[s.y]);
    atomicAdd(&acc[d.z], m[s.z]);
    atomicAdd(&acc[d.w], m[s.w]);
}

// ---------------- score, tanh, partial sum of exp(score) ----------------
__global__ void k_finalize(const float* __restrict__ acc, const float* __restrict__ indeg,
                           const float* __restrict__ bptr, float* __restrict__ score,
                           float* __restrict__ t, float* __restrict__ expsum) {
    int i = blockIdx.x * blockDim.x + threadIdx.x;
    float sc = acc[i] * (1.0f / sqrtf(fmaxf(indeg[i], 1.0f))) + bptr[0];
    score[i] = sc;
    t[i] = tanhf(sc);
    float e = expf(sc);
    #pragma unroll
    for (int off = 32; off > 0; off >>= 1) e += __shfl_down(e, off);
    __shared__ float wsum[4];
    int lane = threadIdx.x & 63, w = threadIdx.x >> 6;
    if (lane == 0) wsum[w] = e;
    __syncthreads();
    if (threadIdx.x == 0)
        atomicAdd(expsum, wsum[0] + wsum[1] + wsum[2] + wsum[3]);
}

// ---------------- per-graph top-K via bitonic sort ----------------
// key = (~ordered(score) << 32) | local_idx ; ascending sort => descending score,
// ascending index on ties (matches jax.lax.top_k). Tail NK entries re-sorted by
// index ascending => stable argsort complement.
__global__ __launch_bounds__(1024) void k_topk(const float* __restrict__ score,
                                               float* __restrict__ perm_f,
                                               float* __restrict__ permc_f,
                                               int* __restrict__ perm_i,
                                               int* __restrict__ permc_i) {
    __shared__ unsigned long long key[NN];
    __shared__ unsigned comp[NK];
    int g = blockIdx.x;
    int tid = threadIdx.x;

    for (int j = tid; j < NN; j += 1024) {
        float sc = score[g * NN + j];
        unsigned u  = __float_as_uint(sc);
        unsigned ok = (u & 0x80000000u) ? ~u : (u | 0x80000000u);  // order-preserving
        unsigned dk = ~ok;                                          // descending
        key[j] = ((unsigned long long)dk << 32) | (unsigned)j;
    }
    __syncthreads();

    for (unsigned k = 2; k <= NN; k <<= 1) {
        for (unsigned j = k >> 1; j > 0; j >>= 1) {
            for (unsigned t2 = tid; t2 < NN; t2 += 1024) {
                unsigned ixj = t2 ^ j;
                if (ixj > t2) {
                    bool up = ((t2 & k) == 0);
                    unsigned long long a = key[t2], b = key[ixj];
                    bool sw = up ? (a > b) : (a < b);
                    if (sw) { key[t2] = b; key[ixj] = a; }
                }
            }
            __syncthreads();
        }
    }

    // selected: ranks [0, NK)
    {
        unsigned local = (unsigned)(key[tid] & 0xFFFFFFFFu);
        int gidx = g * NN + (int)local;
        perm_f[g * NK + tid] = (float)gidx;
        perm_i[g * NK + tid] = gidx;
        comp[tid] = (unsigned)(key[NK + tid] & 0xFFFFFFFFu);
    }
    __syncthreads();

    // sort complement by local index ascending (1024 elements, 1 elem/thread)
    for (unsigned k = 2; k <= NK; k <<= 1) {
        for (unsigned j = k >> 1; j > 0; j >>= 1) {
            unsigned t2 = tid;
            unsigned ixj = t2 ^ j;
            if (ixj > t2) {
                bool up = ((t2 & k) == 0);
                unsigned a = comp[t2], b = comp[ixj];
                bool sw = up ? (a > b) : (a < b);
                if (sw) { comp[t2] = b; comp[ixj] = a; }
            }
            __syncthreads();
        }
    }

    int gidx = g * NN + (int)comp[tid];
    permc_f[g * NK + tid] = (float)gidx;
    permc_i[g * NK + tid] = gidx;
}

// ---------------- gather + scale: out[r] = feat[idx[r]] * t[idx[r]] ----------------
__global__ void k_gather(const float4* __restrict__ feat4, const float* __restrict__ t,
                         const int* __restrict__ idx, float4* __restrict__ out4) {
    int i = blockIdx.x * blockDim.x + threadIdx.x;  // NB*NK*32 threads
    int row = i >> 5, col = i & 31;
    int p = idx[row];
    float tv = t[p];
    float4 v = feat4[(size_t)p * 32 + col];
    out4[i] = make_float4(v.x * tv, v.y * tv, v.z * tv, v.w * tv);
}

// ---------------- feature_full = feature * t ----------------
__global__ void k_full(const float4* __restrict__ feat4, const float* __restrict__ t,
                       float4* __restrict__ out4) {
    int i = blockIdx.x * blockDim.x + threadIdx.x;  // NTOT*32 threads
    int row = i >> 5;
    float tv = t[row];
    float4 v = feat4[i];
    out4[i] = make_float4(v.x * tv, v.y * tv, v.z * tv, v.w * tv);
}

// ---------------- softmax write ----------------
__global__ void k_softmax(const float* __restrict__ score, const float* __restrict__ expsum,
                          float* __restrict__ out) {
    int i = blockIdx.x * blockDim.x + threadIdx.x;
    out[i] = expf(score[i]) / expsum[0];
}

extern "C" void kernel_launch(void* const* d_in, const int* in_sizes, int n_in,
                              void* d_out, int out_size, void* d_ws, size_t ws_size,
                              hipStream_t stream) {
    const float* feat = (const float*)d_in[0];
    const float* W    = (const float*)d_in[1];
    const float* b    = (const float*)d_in[2];
    const int*   src  = (const int*)d_in[3];
    const int*   dst  = (const int*)d_in[4];
    float* out = (float*)d_out;

    // workspace layout (floats)
    float* outdeg = (float*)d_ws;               // NTOT
    float* indeg  = outdeg + NTOT;              // NTOT
    float* acc    = indeg + NTOT;               // NTOT
    float* expsum = acc + NTOT;                 // 64 (pad)
    float* s      = expsum + 64;                // NTOT
    float* m      = s + NTOT;                   // NTOT
    float* score  = m + NTOT;                   // NTOT
    float* t      = score + NTOT;               // NTOT
    int*   perm_i  = (int*)(t + NTOT);          // NB*NK
    int*   permc_i = perm_i + NB * NK;          // NB*NK

    // output layout (floats)
    float* out_dist  = out;                      // NB*NK*ND   = 8388608
    float* out_com   = out_dist + NB * NK * ND;  // 8388608
    float* out_full  = out_com + NB * NK * ND;   // NTOT*ND    = 16777216
    float* out_perm  = out_full + (size_t)NTOT * ND;  // NB*NK = 65536
    float* out_permc = out_perm + NB * NK;       // 65536
    float* out_sm    = out_permc + NB * NK;      // NTOT

    // zero accumulators (outdeg, indeg, acc, expsum are contiguous)
    hipMemsetAsync(d_ws, 0, (size_t)(3 * NTOT + 64) * sizeof(float), stream);

    k_degrees<<<NE / 4 / 256, 256, 0, stream>>>((const int4*)src, (const int4*)dst, outdeg, indeg);
    k_project<<<NTOT * 64 / 256, 256, 0, stream>>>(feat, W, s);
    k_msg<<<NTOT / 256, 256, 0, stream>>>(s, outdeg, m);
    k_scatter<<<NE / 4 / 256, 256, 0, stream>>>((const int4*)src, (const int4*)dst, m, acc);
    k_finalize<<<NTOT / 256, 256, 0, stream>>>(acc, indeg, b, score, t, expsum);
    k_topk<<<NB, 1024, 0, stream>>>(score, out_perm, out_permc, perm_i, permc_i);
    k_gather<<<NB * NK * 32 / 256, 256, 0, stream>>>((const float4*)feat, t, perm_i, (float4*)out_dist);
    k_gather<<<NB * NK * 32 / 256, 256, 0, stream>>>((const float4*)feat, t, permc_i, (float4*)out_com);
    k_full<<<NTOT * 32 / 256, 256, 0, stream>>>((const float4*)feat, t, (float4*)out_full);
    k_softmax<<<NTOT / 256, 256, 0, stream>>>(score, expsum, out_sm);
}

// Round 2
// 367.818 us; speedup vs baseline: 2.1243x; 2.1243x over previous
//
#include <hip/hip_runtime.h>
#include <cstdint>
#include <cstddef>

#define NB 64
#define NN 2048
#define ND 128
#define NK 1024
#define NTOT (NB * NN)        // 131072
#define NE (NB * NN * 32)     // 4194304
#define EPG (NN * 32)         // 65536 edges per graph
#define EPG4 (EPG / 4)        // 16384 int4 per graph

// ---------------- s = feature @ W, one wave (64 lanes) per node ----------------
__global__ void k_project(const float* __restrict__ feat, const float* __restrict__ W,
                          float* __restrict__ s) {
    int gtid = blockIdx.x * blockDim.x + threadIdx.x;
    int node = gtid >> 6;
    int lane = threadIdx.x & 63;
    const float2* f2 = (const float2*)(feat + (size_t)node * ND);
    float2 v  = f2[lane];
    float2 w2 = ((const float2*)W)[lane];
    float val = v.x * w2.x + v.y * w2.y;
    #pragma unroll
    for (int off = 32; off > 0; off >>= 1) val += __shfl_down(val, off);
    if (lane == 0) s[node] = val;
}

// ---------------- per-graph everything: degrees, scatter, score, top-k ----------------
// One block per graph. All accumulation in LDS; zero global atomics except 1
// expsum add per block.
__global__ __launch_bounds__(1024) void k_graph(const int4* __restrict__ src4,
                                                const int4* __restrict__ dst4,
                                                const float* __restrict__ s,
                                                const float* __restrict__ bptr,
                                                float* __restrict__ score_g,
                                                float* __restrict__ t_g,
                                                int* __restrict__ drow,
                                                float* __restrict__ perm_f,
                                                float* __restrict__ permc_f,
                                                float* __restrict__ expsum) {
    __shared__ unsigned ho[NN];       // out-degree hist
    __shared__ unsigned hi2[NN];      // in-degree hist
    __shared__ float    m[NN];        // normalized messages
    __shared__ float    acc[NN];      // scatter accumulator
    __shared__ unsigned long long key[NN];
    __shared__ unsigned comp[NK];
    __shared__ float    wsum[16];

    int g = blockIdx.x;
    int tid = threadIdx.x;
    const int4* sp = src4 + (size_t)g * EPG4;
    const int4* dp = dst4 + (size_t)g * EPG4;

    for (int j = tid; j < NN; j += 1024) { ho[j] = 0u; hi2[j] = 0u; acc[j] = 0.0f; }
    __syncthreads();

    // pass 1: degree histograms (LDS atomics)
    for (int i = tid; i < EPG4; i += 1024) {
        int4 a = sp[i];
        int4 b = dp[i];
        atomicAdd(&ho[a.x & (NN - 1)], 1u); atomicAdd(&ho[a.y & (NN - 1)], 1u);
        atomicAdd(&ho[a.z & (NN - 1)], 1u); atomicAdd(&ho[a.w & (NN - 1)], 1u);
        atomicAdd(&hi2[b.x & (NN - 1)], 1u); atomicAdd(&hi2[b.y & (NN - 1)], 1u);
        atomicAdd(&hi2[b.z & (NN - 1)], 1u); atomicAdd(&hi2[b.w & (NN - 1)], 1u);
    }
    __syncthreads();

    // m = s * rsqrt(max(outdeg,1))
    for (int j = tid; j < NN; j += 1024)
        m[j] = s[g * NN + j] * rsqrtf(fmaxf((float)ho[j], 1.0f));
    __syncthreads();

    // pass 2: scatter (edges re-read from L2; LDS float atomics)
    for (int i = tid; i < EPG4; i += 1024) {
        int4 a = sp[i];
        int4 b = dp[i];
        atomicAdd(&acc[b.x & (NN - 1)], m[a.x & (NN - 1)]);
        atomicAdd(&acc[b.y & (NN - 1)], m[a.y & (NN - 1)]);
        atomicAdd(&acc[b.z & (NN - 1)], m[a.z & (NN - 1)]);
        atomicAdd(&acc[b.w & (NN - 1)], m[a.w & (NN - 1)]);
    }
    __syncthreads();

    // score, tanh, exp-partial, sort keys
    float bb = bptr[0];
    float esum = 0.0f;
    for (int j = tid; j < NN; j += 1024) {
        float sc = acc[j] * rsqrtf(fmaxf((float)hi2[j], 1.0f)) + bb;
        score_g[g * NN + j] = sc;
        t_g[g * NN + j] = tanhf(sc);
        esum += expf(sc);
        unsigned u  = __float_as_uint(sc);
        unsigned ok = (u & 0x80000000u) ? ~u : (u | 0x80000000u);  // order-preserving
        key[j] = ((unsigned long long)(~ok) << 32) | (unsigned)j;  // descending score, asc idx
    }
    #pragma unroll
    for (int off = 32; off > 0; off >>= 1) esum += __shfl_down(esum, off);
    int lane = tid & 63, w = tid >> 6;
    if (lane == 0) wsum[w] = esum;
    __syncthreads();
    if (tid == 0) {
        float tot = 0.0f;
        #pragma unroll
        for (int i = 0; i < 16; i++) tot += wsum[i];
        atomicAdd(expsum, tot);
    }

    // bitonic sort of 2048 keys (ascending == descending score)
    for (unsigned k = 2; k <= NN; k <<= 1) {
        for (unsigned j = k >> 1; j > 0; j >>= 1) {
            for (unsigned t2 = tid; t2 < NN; t2 += 1024) {
                unsigned ixj = t2 ^ j;
                if (ixj > t2) {
                    bool up = ((t2 & k) == 0);
                    unsigned long long a = key[t2], b = key[ixj];
                    bool sw = up ? (a > b) : (a < b);
                    if (sw) { key[t2] = b; key[ixj] = a; }
                }
            }
            __syncthreads();
        }
    }

    // selected ranks [0, NK)
    {
        unsigned local = (unsigned)(key[tid] & 0xFFFFFFFFu);
        int gidx = g * NN + (int)local;
        perm_f[g * NK + tid] = (float)gidx;
        drow[gidx] = g * NK + tid;                       // dist region row
        comp[tid] = (unsigned)(key[NK + tid] & 0xFFFFFFFFu);
    }
    __syncthreads();

    // sort complement by local index ascending (stable-argsort semantics)
    for (unsigned k = 2; k <= NK; k <<= 1) {
        for (unsigned j = k >> 1; j > 0; j >>= 1) {
            unsigned t2 = tid;
            unsigned ixj = t2 ^ j;
            if (ixj > t2) {
                bool up = ((t2 & k) == 0);
                unsigned a = comp[t2], b = comp[ixj];
                bool sw = up ? (a > b) : (a < b);
                if (sw) { comp[t2] = b; comp[ixj] = a; }
            }
            __syncthreads();
        }
    }

    {
        int gidx = g * NN + (int)comp[tid];
        permc_f[g * NK + tid] = (float)gidx;
        drow[gidx] = NB * NK + g * NK + tid;             // com region row
    }
}

// ---------------- emit: one feature pass -> out_full + out_dist|out_com ----------------
__global__ void k_emit(const float4* __restrict__ feat4, const float* __restrict__ t,
                       const int* __restrict__ drow, float4* __restrict__ out_full,
                       float4* __restrict__ out_distcom) {
    int i = blockIdx.x * blockDim.x + threadIdx.x;  // NTOT*32 threads
    int row = i >> 5, col = i & 31;
    float tv = t[row];
    float4 v = feat4[i];
    float4 r = make_float4(v.x * tv, v.y * tv, v.z * tv, v.w * tv);
    out_full[i] = r;
    out_distcom[(size_t)drow[row] * 32 + col] = r;
}

// ---------------- softmax write ----------------
__global__ void k_softmax(const float* __restrict__ score, const float* __restrict__ expsum,
                          float* __restrict__ out) {
    int i = blockIdx.x * blockDim.x + threadIdx.x;
    out[i] = expf(score[i]) / expsum[0];
}

extern "C" void kernel_launch(void* const* d_in, const int* in_sizes, int n_in,
                              void* d_out, int out_size, void* d_ws, size_t ws_size,
                              hipStream_t stream) {
    const float* feat = (const float*)d_in[0];
    const float* W    = (const float*)d_in[1];
    const float* b    = (const float*)d_in[2];
    const int*   src  = (const int*)d_in[3];
    const int*   dst  = (const int*)d_in[4];
    float* out = (float*)d_out;

    // workspace layout
    float* expsum = (float*)d_ws;               // 64 (pad)
    float* s      = expsum + 64;                // NTOT
    float* score  = s + NTOT;                   // NTOT
    float* t      = score + NTOT;               // NTOT
    int*   drow   = (int*)(t + NTOT);           // NTOT

    // output layout (floats)
    float* out_dist  = out;                           // NB*NK*ND (dist|com contiguous)
    float* out_full  = out + 2 * (size_t)NB * NK * ND;
    float* out_perm  = out_full + (size_t)NTOT * ND;  // NB*NK
    float* out_permc = out_perm + NB * NK;            // NB*NK
    float* out_sm    = out_permc + NB * NK;           // NTOT

    hipMemsetAsync(expsum, 0, 64 * sizeof(float), stream);

    k_project<<<NTOT * 64 / 256, 256, 0, stream>>>(feat, W, s);
    k_graph<<<NB, 1024, 0, stream>>>((const int4*)src, (const int4*)dst, s, b,
                                     score, t, drow, out_perm, out_permc, expsum);
    k_emit<<<NTOT * 32 / 256, 256, 0, stream>>>((const float4*)feat, t, drow,
                                                (float4*)out_full, (float4*)out_dist);
    k_softmax<<<NTOT / 256, 256, 0, stream>>>(score, expsum, out_sm);
}

// Round 3
// 303.110 us; speedup vs baseline: 2.5778x; 1.2135x over previous
//
#include <hip/hip_runtime.h>
#include <cstdint>
#include <cstddef>

#define NB 64
#define NN 2048
#define ND 128
#define NK 1024
#define NTOT (NB * NN)        // 131072
#define NE (NB * NN * 32)     // 4194304
#define EPG (NN * 32)         // 65536 edges per graph
#define EPG4 (EPG / 4)        // 16384 int4 per graph
#define P 8                   // slices per graph
#define SLICE4 (EPG4 / P)     // 2048 int4 per slice

// ---------------- s = feature @ W, one wave (64 lanes) per node ----------------
__global__ void k_project(const float* __restrict__ feat, const float* __restrict__ W,
                          float* __restrict__ s) {
    int gtid = blockIdx.x * blockDim.x + threadIdx.x;
    int node = gtid >> 6;
    int lane = threadIdx.x & 63;
    const float2* f2 = (const float2*)(feat + (size_t)node * ND);
    float2 v  = f2[lane];
    float2 w2 = ((const float2*)W)[lane];
    float val = v.x * w2.x + v.y * w2.y;
    #pragma unroll
    for (int off = 32; off > 0; off >>= 1) val += __shfl_down(val, off);
    if (lane == 0) s[node] = val;
}

// ---------------- per-slice degree histograms (LDS), partials to global ----------------
__global__ __launch_bounds__(256) void k_hist(const int4* __restrict__ src4,
                                              const int4* __restrict__ dst4,
                                              unsigned* __restrict__ part_o,
                                              unsigned* __restrict__ part_i) {
    __shared__ unsigned ho[NN];
    __shared__ unsigned hi2[NN];
    int blk = blockIdx.x, tid = threadIdx.x;
    for (int j = tid; j < NN; j += 256) { ho[j] = 0u; hi2[j] = 0u; }
    __syncthreads();
    const int4* sp = src4 + (size_t)blk * SLICE4;
    const int4* dp = dst4 + (size_t)blk * SLICE4;
    for (int i = tid; i < SLICE4; i += 256) {
        int4 a = sp[i];
        int4 b = dp[i];
        atomicAdd(&ho[a.x & (NN - 1)], 1u); atomicAdd(&ho[a.y & (NN - 1)], 1u);
        atomicAdd(&ho[a.z & (NN - 1)], 1u); atomicAdd(&ho[a.w & (NN - 1)], 1u);
        atomicAdd(&hi2[b.x & (NN - 1)], 1u); atomicAdd(&hi2[b.y & (NN - 1)], 1u);
        atomicAdd(&hi2[b.z & (NN - 1)], 1u); atomicAdd(&hi2[b.w & (NN - 1)], 1u);
    }
    __syncthreads();
    unsigned* po = part_o + (size_t)blk * NN;
    unsigned* pi = part_i + (size_t)blk * NN;
    for (int j = tid; j < NN; j += 256) { po[j] = ho[j]; pi[j] = hi2[j]; }
}

// ---------------- reduce degree partials -> m, inv_in ----------------
__global__ void k_msg(const unsigned* __restrict__ part_o, const unsigned* __restrict__ part_i,
                      const float* __restrict__ s, float* __restrict__ m,
                      float* __restrict__ inv_in) {
    int node = blockIdx.x * blockDim.x + threadIdx.x;
    int g = node >> 11, local = node & (NN - 1);
    const unsigned* po = part_o + (size_t)g * P * NN + local;
    const unsigned* pi = part_i + (size_t)g * P * NN + local;
    unsigned od = 0, id2 = 0;
    #pragma unroll
    for (int p = 0; p < P; p++) { od += po[(size_t)p * NN]; id2 += pi[(size_t)p * NN]; }
    m[node] = s[node] * rsqrtf(fmaxf((float)od, 1.0f));
    inv_in[node] = rsqrtf(fmaxf((float)id2, 1.0f));
}

// ---------------- per-slice scatter (LDS), partials to global ----------------
__global__ __launch_bounds__(256) void k_scatter(const int4* __restrict__ src4,
                                                 const int4* __restrict__ dst4,
                                                 const float* __restrict__ m,
                                                 float* __restrict__ part_a) {
    __shared__ float ms[NN];
    __shared__ float acc[NN];
    int blk = blockIdx.x, tid = threadIdx.x;
    int g = blk >> 3;   // blk / P
    for (int j = tid; j < NN; j += 256) { ms[j] = m[g * NN + j]; acc[j] = 0.0f; }
    __syncthreads();
    const int4* sp = src4 + (size_t)blk * SLICE4;
    const int4* dp = dst4 + (size_t)blk * SLICE4;
    for (int i = tid; i < SLICE4; i += 256) {
        int4 a = sp[i];
        int4 b = dp[i];
        atomicAdd(&acc[b.x & (NN - 1)], ms[a.x & (NN - 1)]);
        atomicAdd(&acc[b.y & (NN - 1)], ms[a.y & (NN - 1)]);
        atomicAdd(&acc[b.z & (NN - 1)], ms[a.z & (NN - 1)]);
        atomicAdd(&acc[b.w & (NN - 1)], ms[a.w & (NN - 1)]);
    }
    __syncthreads();
    float* pa = part_a + (size_t)blk * NN;
    for (int j = tid; j < NN; j += 256) pa[j] = acc[j];
}

// ---------------- reduce scatter partials, score, tanh, expsum, top-k ----------------
__global__ __launch_bounds__(1024) void k_final(const float* __restrict__ part_a,
                                                const float* __restrict__ inv_in,
                                                const float* __restrict__ bptr,
                                                float* __restrict__ score_g,
                                                float* __restrict__ t_g,
                                                int* __restrict__ drow,
                                                float* __restrict__ perm_f,
                                                float* __restrict__ permc_f,
                                                float* __restrict__ expsum) {
    __shared__ unsigned long long key[NN];
    __shared__ unsigned comp[NK];
    __shared__ float wsum[16];
    int g = blockIdx.x, tid = threadIdx.x;

    float bb = bptr[0];
    float esum = 0.0f;
    for (int j = tid; j < NN; j += 1024) {
        const float* pa = part_a + (size_t)g * P * NN + j;
        float a = 0.0f;
        #pragma unroll
        for (int p = 0; p < P; p++) a += pa[(size_t)p * NN];   // fixed order: deterministic
        float sc = a * inv_in[g * NN + j] + bb;
        score_g[g * NN + j] = sc;
        t_g[g * NN + j] = tanhf(sc);
        esum += expf(sc);
        unsigned u  = __float_as_uint(sc);
        unsigned ok = (u & 0x80000000u) ? ~u : (u | 0x80000000u);  // order-preserving
        key[j] = ((unsigned long long)(~ok) << 32) | (unsigned)j;  // desc score, asc idx
    }
    #pragma unroll
    for (int off = 32; off > 0; off >>= 1) esum += __shfl_down(esum, off);
    int lane = tid & 63, w = tid >> 6;
    if (lane == 0) wsum[w] = esum;
    __syncthreads();
    if (tid == 0) {
        float tot = 0.0f;
        #pragma unroll
        for (int i = 0; i < 16; i++) tot += wsum[i];
        atomicAdd(expsum, tot);
    }

    // bitonic sort of 2048 keys ascending (== descending score)
    for (unsigned k = 2; k <= NN; k <<= 1) {
        for (unsigned j = k >> 1; j > 0; j >>= 1) {
            for (unsigned t2 = tid; t2 < NN; t2 += 1024) {
                unsigned ixj = t2 ^ j;
                if (ixj > t2) {
                    bool up = ((t2 & k) == 0);
                    unsigned long long a = key[t2], b = key[ixj];
                    bool sw = up ? (a > b) : (a < b);
                    if (sw) { key[t2] = b; key[ixj] = a; }
                }
            }
            __syncthreads();
        }
    }

    {
        unsigned local = (unsigned)(key[tid] & 0xFFFFFFFFu);
        int gidx = g * NN + (int)local;
        perm_f[g * NK + tid] = (float)gidx;
        drow[gidx] = g * NK + tid;                       // dist region row
        comp[tid] = (unsigned)(key[NK + tid] & 0xFFFFFFFFu);
    }
    __syncthreads();

    // sort complement by local index ascending (stable-argsort semantics)
    for (unsigned k = 2; k <= NK; k <<= 1) {
        for (unsigned j = k >> 1; j > 0; j >>= 1) {
            unsigned t2 = tid;
            unsigned ixj = t2 ^ j;
            if (ixj > t2) {
                bool up = ((t2 & k) == 0);
                unsigned a = comp[t2], b = comp[ixj];
                bool sw = up ? (a > b) : (a < b);
                if (sw) { comp[t2] = b; comp[ixj] = a; }
            }
            __syncthreads();
        }
    }

    {
        int gidx = g * NN + (int)comp[tid];
        permc_f[g * NK + tid] = (float)gidx;
        drow[gidx] = NB * NK + g * NK + tid;             // com region row
    }
}

// ---------------- emit: one feature pass -> out_full + out_dist|out_com ----------------
__global__ void k_emit(const float4* __restrict__ feat4, const float* __restrict__ t,
                       const int* __restrict__ drow, float4* __restrict__ out_full,
                       float4* __restrict__ out_distcom) {
    int i = blockIdx.x * blockDim.x + threadIdx.x;  // NTOT*32 threads
    int row = i >> 5, col = i & 31;
    float tv = t[row];
    float4 v = feat4[i];
    float4 r = make_float4(v.x * tv, v.y * tv, v.z * tv, v.w * tv);
    out_full[i] = r;
    out_distcom[(size_t)drow[row] * 32 + col] = r;
}

// ---------------- softmax write ----------------
__global__ void k_softmax(const float* __restrict__ score, const float* __restrict__ expsum,
                          float* __restrict__ out) {
    int i = blockIdx.x * blockDim.x + threadIdx.x;
    out[i] = expf(score[i]) / expsum[0];
}

extern "C" void kernel_launch(void* const* d_in, const int* in_sizes, int n_in,
                              void* d_out, int out_size, void* d_ws, size_t ws_size,
                              hipStream_t stream) {
    const float* feat = (const float*)d_in[0];
    const float* W    = (const float*)d_in[1];
    const float* b    = (const float*)d_in[2];
    const int*   src  = (const int*)d_in[3];
    const int*   dst  = (const int*)d_in[4];
    float* out = (float*)d_out;

    // workspace layout
    float* expsum = (float*)d_ws;                    // 64 (pad)
    float* s      = expsum + 64;                     // NTOT
    float* score  = s + NTOT;                        // NTOT
    float* t      = score + NTOT;                    // NTOT
    float* m      = t + NTOT;                        // NTOT
    float* inv_in = m + NTOT;                        // NTOT
    int*   drow   = (int*)(inv_in + NTOT);           // NTOT
    unsigned* part_o = (unsigned*)(drow + NTOT);     // NB*P*NN = 1M
    unsigned* part_i = part_o + (size_t)NB * P * NN; // 1M
    float* part_a    = (float*)(part_i + (size_t)NB * P * NN); // 1M

    // output layout (floats)
    float* out_dist  = out;                           // NB*NK*ND (dist|com contiguous)
    float* out_full  = out + 2 * (size_t)NB * NK * ND;
    float* out_perm  = out_full + (size_t)NTOT * ND;  // NB*NK
    float* out_permc = out_perm + NB * NK;            // NB*NK
    float* out_sm    = out_permc + NB * NK;           // NTOT

    hipMemsetAsync(expsum, 0, 64 * sizeof(float), stream);

    k_project<<<NTOT * 64 / 256, 256, 0, stream>>>(feat, W, s);
    k_hist<<<NB * P, 256, 0, stream>>>((const int4*)src, (const int4*)dst, part_o, part_i);
    k_msg<<<NTOT / 256, 256, 0, stream>>>(part_o, part_i, s, m, inv_in);
    k_scatter<<<NB * P, 256, 0, stream>>>((const int4*)src, (const int4*)dst, m, part_a);
    k_final<<<NB, 1024, 0, stream>>>(part_a, inv_in, b, score, t, drow,
                                     out_perm, out_permc, expsum);
    k_emit<<<NTOT * 32 / 256, 256, 0, stream>>>((const float4*)feat, t, drow,
                                                (float4*)out_full, (float4*)out_dist);
    k_softmax<<<NTOT / 256, 256, 0, stream>>>(score, expsum, out_sm);
}